// Round 7
// baseline (169.107 us; speedup 1.0000x reference)
//
#include <hip/hip_runtime.h>

#define IN_D 112
#define OUT_D 111
#define MDIM 16

// Round-7 restructure: maximum device-level concurrency, minimal per-wave
// phase structure.
//
// Rounds 1-6 post-mortem: time invariant at 52-59 us across SIX structures
// that varied per-wave memory-level parallelism from ~1 to ~160 cache lines
// (rolling register prefetch / LDS-M / AGPR-pinned M / 10-deep hoisted loads
// / zero-VGPR global_load_lds DMA). M supply and per-wave MLP are both
// falsified as bottlenecks. The invariant: ~11 resident waves/CU issuing
// loads in short bursts (phase-locked load->wait->compute->store), so
// time-averaged in-flight bytes ~4 KB/CU << the 9.2 KB/CU Little's-law
// requirement for 6.3 TB/s. m13's 6.3 TB/s copy: ~32 continuously-issuing
// waves/CU.
//
// Fix: DC=1 flat kernel. One output row-segment per wave-step: 4 independent
// 1KB loads -> compute -> 1KB store -> exit. No k-loop, no prefetch buffer,
// no post-load barrier. 98568 waves (385/CU, 4x round 5) of short
// independent work arriving continuously = copy-kernel issue shape.
// Redundant d-pair re-reads (2x logical input) are L2/L3-absorbed exactly
// like the existing h-overlap (FETCH stays ~100 MB).
__device__ __forceinline__ float4 f4add(float4 a, float4 b) {
    return make_float4(a.x + b.x, a.y + b.y, a.z + b.z, a.w + b.w);
}
__device__ __forceinline__ float4 shfl_down4(float4 v) {
    return make_float4(__shfl_down(v.x, 4, 64), __shfl_down(v.y, 4, 64),
                       __shfl_down(v.z, 4, 64), __shfl_down(v.w, 4, 64));
}

// DPP quad_perm broadcast of lane j within each quad: ctrl = j*0x55.
template <int CTRL>
__device__ __forceinline__ float dppf(float v) {
    return __int_as_float(
        __builtin_amdgcn_mov_dpp(__float_as_int(v), CTRL, 0xF, 0xF, false));
}
template <int CTRL>
__device__ __forceinline__ float4 dpp4(float4 v) {
    return make_float4(dppf<CTRL>(v.x), dppf<CTRL>(v.y),
                       dppf<CTRL>(v.z), dppf<CTRL>(v.w));
}
__device__ __forceinline__ float dot4(float4 a, float4 b) {
    return a.x * b.x + a.y * b.y + a.z * b.z + a.w * b.w;
}

__global__ __launch_bounds__(256)
void spatial_dual_desc_kernel(const float* __restrict__ x,
                              const float* __restrict__ Mg,
                              float* __restrict__ out) {
    const int lane = threadIdx.x & 63;
    const int wid  = threadIdx.x >> 6;          // 0..3
    const int g    = blockIdx.x * 4 + wid;      // column-group 0..7
    const int ci   = lane >> 2;                 // 0..15
    const int q    = lane & 3;                  // 0..3
    const int col  = g * 15 + ci;               // candidate output column
    const int c    = (col < IN_D) ? col : (IN_D - 1);
    const int h    = blockIdx.y;                // 0..110  (rows h, h+1 in range)
    const int d    = blockIdx.z;                // 0..110  (slabs d, d+1 in range)

    // Stage M once per block; sync happens BEFORE the slab loads so no
    // barrier ever drains them.
    __shared__ float Ms[MDIM * MDIM];
    Ms[threadIdx.x] = Mg[threadIdx.x];
    __syncthreads();

    const size_t row_stride  = (size_t)IN_D * MDIM;          // h step (floats)
    const size_t slab_stride = (size_t)IN_D * row_stride;    // d step (floats)
    const float* p = x + ((size_t)d * IN_D * IN_D + (size_t)h * IN_D + c) * MDIM + 4 * q;

    // 4 independent 1KB loads (rows h,h+1 of slabs d,d+1). Compiler places
    // counted vmcnt before first use; no barrier, no buffer.
    float4 a0 = *(const float4*)(p);
    float4 a1 = *(const float4*)(p + row_stride);
    float4 b0 = *(const float4*)(p + slab_stride);
    float4 b1 = *(const float4*)(p + slab_stride + row_stride);

    // 2x2x1 window sum in d,h; then w-pair via lane+4 shift.
    float4 s4 = f4add(f4add(a0, a1), f4add(b0, b1));
    float4 w4 = f4add(s4, shfl_down4(s4));

    // Broadcast each quad's float4 to its 4 lanes: every lane now holds the
    // full 16-component window vector in natural order.
    float4 u0 = dpp4<0x00>(w4);
    float4 u1 = dpp4<0x55>(w4);
    float4 u2 = dpp4<0xAA>(w4);
    float4 u3 = dpp4<0xFF>(w4);

    // o[i] = (1/8) * dot(u, M[4q+i][:]). M rows read straight from LDS
    // (4 distinct addresses per read across the wave -> broadcast-class,
    // conflict-free; per-output DS rate identical to round 2 which showed
    // DS slack).
    float o[4];
#pragma unroll
    for (int i = 0; i < 4; ++i) {
        const float4* Mr = (const float4*)(&Ms[(4 * q + i) * MDIM]);
        o[i] = (dot4(u0, Mr[0]) + dot4(u1, Mr[1]) +
                dot4(u2, Mr[2]) + dot4(u3, Mr[3])) * 0.125f;
    }

    if (ci < 15 && col < OUT_D) {
        *(float4*)(out + (((size_t)d * OUT_D + h) * OUT_D + col) * MDIM + 4 * q)
            = make_float4(o[0], o[1], o[2], o[3]);
    }
}

extern "C" void kernel_launch(void* const* d_in, const int* in_sizes, int n_in,
                              void* d_out, int out_size, void* d_ws, size_t ws_size,
                              hipStream_t stream) {
    const float* x = (const float*)d_in[0];   // (112,112,112,16) fp32
    const float* M = (const float*)d_in[1];   // (16,16) fp32
    float* out = (float*)d_out;               // (111^3, 16) fp32

    dim3 block(256, 1, 1);
    dim3 grid(2, OUT_D, OUT_D);               // 2 x 111 x 111 = 24642 blocks
    spatial_dual_desc_kernel<<<grid, block, 0, stream>>>(x, M, out);
}